// Round 1
// baseline (433.300 us; speedup 1.0000x reference)
//
#include <hip/hip_runtime.h>

// out[b,s,f] = sx[b,s] * sk[f] * sum_d qx[b,s,d] * qk[d,f]
// qx = clip(round(x/sx),-127,127), sx = max(amax_row,1e-6)/127   (per activation row)
// qk = clip(round(k/sk),-127,127), sk = max(amax_col,1e-6)/127   (per kernel column)
// Exact int32 accumulation via v_mfma_i32_16x16x64_i8.

#define M_DIM 8192
#define K_DIM 4096
#define N_DIM 4096

typedef int v4i __attribute__((ext_vector_type(4)));
typedef __attribute__((address_space(3))) void lds_void_t;
typedef const __attribute__((address_space(1))) void g_void_t;

// ---------------- activation quantization: one block per row ----------------
__global__ void quant_act(const float* __restrict__ X,
                          signed char* __restrict__ Aq,
                          float* __restrict__ sx) {
  const int row = blockIdx.x;
  const int t = threadIdx.x;  // 256
  const float* xr = X + (size_t)row * K_DIM;
  float4 v[4];
  float am = 0.f;
#pragma unroll
  for (int c = 0; c < 4; ++c) {
    v[c] = ((const float4*)xr)[c * 256 + t];
    am = fmaxf(am, fmaxf(fmaxf(fabsf(v[c].x), fabsf(v[c].y)),
                         fmaxf(fabsf(v[c].z), fabsf(v[c].w))));
  }
#pragma unroll
  for (int off = 32; off > 0; off >>= 1)
    am = fmaxf(am, __shfl_down(am, off));
  __shared__ float red[4];
  __shared__ float s_inv;
  if ((t & 63) == 0) red[t >> 6] = am;
  __syncthreads();
  if (t == 0) {
    float m = fmaxf(fmaxf(red[0], red[1]), fmaxf(red[2], red[3]));
    float scale = fmaxf(m, 1e-6f) / 127.0f;  // matches ref: max(amax,1e-6)/127
    sx[row] = scale;
    s_inv = 1.0f / scale;  // one divide per row (per-thread divides cost ~50us)
  }
  __syncthreads();
  const float inv = s_inv;
  int* aq32 = (int*)(Aq + (size_t)row * K_DIM);
#pragma unroll
  for (int c = 0; c < 4; ++c) {
    // round (RNE, matches jnp.round) then clip to +-127, pack 4 x int8
    int q0 = (int)fminf(fmaxf(rintf(v[c].x * inv), -127.f), 127.f);
    int q1 = (int)fminf(fmaxf(rintf(v[c].y * inv), -127.f), 127.f);
    int q2 = (int)fminf(fmaxf(rintf(v[c].z * inv), -127.f), 127.f);
    int q3 = (int)fminf(fmaxf(rintf(v[c].w * inv), -127.f), 127.f);
    aq32[c * 256 + t] = (q0 & 255) | ((q1 & 255) << 8) | ((q2 & 255) << 16) | (q3 << 24);
  }
}

// ---------------- weight column-amax: 512 partial blocks + combine ----------------
__global__ void wk_amax_part(const float* __restrict__ Kmat, float* __restrict__ part) {
  // grid (16, 32): x = 256-col stripe, y = 128-row (d) slice
  const int f = blockIdx.x * 256 + threadIdx.x;
  const float* p = Kmat + (size_t)(blockIdx.y * 128) * N_DIM + f;
  float a0 = 0.f, a1 = 0.f, a2 = 0.f, a3 = 0.f;
#pragma unroll 4
  for (int i = 0; i < 32; ++i) {
    a0 = fmaxf(a0, fabsf(p[0 * N_DIM]));
    a1 = fmaxf(a1, fabsf(p[1 * N_DIM]));
    a2 = fmaxf(a2, fabsf(p[2 * N_DIM]));
    a3 = fmaxf(a3, fabsf(p[3 * N_DIM]));
    p += 4 * N_DIM;
  }
  part[(size_t)blockIdx.y * N_DIM + f] = fmaxf(fmaxf(a0, a1), fmaxf(a2, a3));
}

__global__ void wk_amax_comb(const float* __restrict__ part,
                             float* __restrict__ sk, float* __restrict__ skinv) {
  const int f = blockIdx.x * 256 + threadIdx.x;
  float am = 0.f;
#pragma unroll
  for (int s = 0; s < 32; ++s) am = fmaxf(am, part[(size_t)s * N_DIM + f]);
  float scale = fmaxf(am, 1e-6f) / 127.0f;
  sk[f] = scale;
  skinv[f] = 1.0f / scale;  // all divides happen here (4096 total)
}

// ---------------- weight quant + transpose: 64x64 tiles via LDS ----------------
__global__ void wk_quant(const float* __restrict__ Kmat,
                         const float* __restrict__ skinv,
                         signed char* __restrict__ BqT) {
  const int f0 = (blockIdx.x & 63) * 64;
  const int d0 = (blockIdx.x >> 6) * 64;
  const int t = threadIdx.x;
  const int fl = t & 63;
  const int dl0 = t >> 6;  // 0..3
  __shared__ signed char tile[64 * 68];  // stride 68: 17*f mod 32 -> all banks, 2-way max (free)
  const float inv = skinv[f0 + fl];
#pragma unroll
  for (int c = 0; c < 16; ++c) {
    const int dl = c * 4 + dl0;
    float vv = Kmat[(size_t)(d0 + dl) * N_DIM + f0 + fl];
    float q = fminf(fmaxf(rintf(vv * inv), -127.f), 127.f);
    tile[fl * 68 + dl] = (signed char)(int)q;
  }
  __syncthreads();
#pragma unroll
  for (int c = 0; c < 4; ++c) {
    const int idx = c * 256 + t;   // 1024 dwords
    const int fr = idx >> 4;       // 0..63
    const int d4 = idx & 15;       // dword within 64-byte row
    unsigned int w = *(const unsigned int*)&tile[fr * 68 + d4 * 4];  // 68 % 4 == 0, aligned
    *(unsigned int*)&BqT[(size_t)(f0 + fr) * K_DIM + d0 + d4 * 4] = w;
  }
}

// ---------------- int8 GEMM: 128x128 tile, BK=64, 4 waves, 16x16x64 i8 MFMA ----------------
__global__ __launch_bounds__(256, 2) void gemm_i8(
    const signed char* __restrict__ Aq, const signed char* __restrict__ BqT,
    const float* __restrict__ sx, const float* __restrict__ sk,
    float* __restrict__ C) {
  const int n0 = blockIdx.x * 128;
  const int m0 = blockIdx.y * 128;
  const int t = threadIdx.x;
  const int lane = t & 63;
  const int wave = t >> 6;
  const int wm = (wave >> 1) * 64;  // wave's 64x64 sub-tile
  const int wn = (wave & 1) * 64;
  const int lrow = lane & 15;
  const int lq = lane >> 4;  // quarter-wave id

  __shared__ __align__(16) signed char lA[128 * 64];  // [m][k] int8
  __shared__ __align__(16) signed char lB[128 * 64];  // [n][k] int8

  v4i acc[4][4];
#pragma unroll
  for (int i = 0; i < 4; ++i)
#pragma unroll
    for (int j = 0; j < 4; ++j) acc[i][j] = (v4i){0, 0, 0, 0};

  const signed char* Abase = Aq + (size_t)m0 * K_DIM;
  const signed char* Bbase = BqT + (size_t)n0 * K_DIM;

  int aoff[4], boff[4];
#pragma unroll
  for (int i = 0; i < 4; ++i) {
    aoff[i] = (wm + i * 16 + lrow) * 64 + lq * 16;
    boff[i] = (wn + i * 16 + lrow) * 64 + lq * 16;
  }

  for (int kb = 0; kb < K_DIM; kb += 64) {
    // stage 8KB A + 8KB B: 512 16B chunks each, lane-contiguous per wave
#pragma unroll
    for (int c = 0; c < 2; ++c) {
      const int i = c * 256 + t;
      const int r = i >> 2;
      const int kc = (i & 3) * 16;
      __builtin_amdgcn_global_load_lds(
          (g_void_t*)(Abase + (size_t)r * K_DIM + kb + kc),
          (lds_void_t*)(lA + i * 16), 16, 0, 0);
      __builtin_amdgcn_global_load_lds(
          (g_void_t*)(Bbase + (size_t)r * K_DIM + kb + kc),
          (lds_void_t*)(lB + i * 16), 16, 0, 0);
    }
    __syncthreads();  // compiler emits vmcnt(0) drain before barrier
    v4i af[4], bf[4];
#pragma unroll
    for (int i = 0; i < 4; ++i) af[i] = *(const v4i*)(lA + aoff[i]);
#pragma unroll
    for (int i = 0; i < 4; ++i) bf[i] = *(const v4i*)(lB + boff[i]);
#pragma unroll
    for (int mi = 0; mi < 4; ++mi)
#pragma unroll
      for (int ni = 0; ni < 4; ++ni)
        acc[mi][ni] =
            __builtin_amdgcn_mfma_i32_16x16x64_i8(af[mi], bf[ni], acc[mi][ni], 0, 0, 0);
    __syncthreads();
  }

  // epilogue: C/D layout col=lane&15, row=(lane>>4)*4+reg (dtype-independent)
#pragma unroll
  for (int mi = 0; mi < 4; ++mi) {
#pragma unroll
    for (int ni = 0; ni < 4; ++ni) {
      const int gn = n0 + wn + ni * 16 + lrow;
      const float skv = sk[gn];
#pragma unroll
      for (int r = 0; r < 4; ++r) {
        const int gm = m0 + wm + mi * 16 + lq * 4 + r;
        C[(size_t)gm * N_DIM + gn] = (float)acc[mi][ni][r] * sx[gm] * skv;
      }
    }
  }
}

// ---------------- launch ----------------
extern "C" void kernel_launch(void* const* d_in, const int* in_sizes, int n_in,
                              void* d_out, int out_size, void* d_ws, size_t ws_size,
                              hipStream_t stream) {
  const float* X = (const float*)d_in[0];  // [4,2048,4096] fp32
  const float* W = (const float*)d_in[1];  // [4096,4096] fp32
  float* out = (float*)d_out;              // [4,2048,4096] fp32
  char* ws = (char*)d_ws;

  // workspace layout (~48.6 MB total)
  signed char* Aq = (signed char*)ws;                       // 32 MB  [8192][4096] i8
  signed char* BqT = (signed char*)(ws + 33554432);         // 16 MB  [4096 f][4096 d] i8
  float* sx = (float*)(ws + 50331648);                      // 32 KB
  float* sk = (float*)(ws + 50364416);                      // 16 KB
  float* skinv = (float*)(ws + 50380800);                   // 16 KB
  float* part = (float*)(ws + 50397184);                    // 512 KB [32][4096]

  quant_act<<<M_DIM, 256, 0, stream>>>(X, Aq, sx);
  wk_amax_part<<<dim3(16, 32), 256, 0, stream>>>(W, part);
  wk_amax_comb<<<16, 256, 0, stream>>>(part, sk, skinv);
  wk_quant<<<4096, 256, 0, stream>>>(W, skinv, BqT);
  gemm_i8<<<dim3(N_DIM / 128, M_DIM / 128), 256, 0, stream>>>(Aq, BqT, sx, sk, out);
}

// Round 2
// 419.065 us; speedup vs baseline: 1.0340x; 1.0340x over previous
//
#include <hip/hip_runtime.h>

// out[b,s,f] = sx[b,s] * sk[f] * sum_d qx[b,s,d] * qk[d,f]
// Exact int32 accumulation via v_mfma_i32_16x16x64_i8.
//
// R2 change: A/B stored globally in MFMA-fragment order
//   T[tile16][kslice16][row16][16B]  (one 16-row x 16-byte-k chunk = 256 B)
// so GEMM staging is 1KB-contiguous per wave-instr AND ds_read_b128 fragment
// reads are base+lane*16 contiguous => zero bank conflicts (R1: 1.68e7
// conflicts = 4 extra cyc per read, LDS-busy ~62% of GEMM wall).
// BK=64->128: halves barrier count (32 MFMA/barrier), 32 KB LDS/block.

#define M_DIM 8192
#define K_DIM 4096
#define N_DIM 4096

typedef int v4i __attribute__((ext_vector_type(4)));
typedef __attribute__((address_space(3))) void lds_void_t;
typedef const __attribute__((address_space(1))) void g_void_t;

// ---------------- activation quantization: one block per row ----------------
// Writes A_t[mt][ks][r][16]: mt=row>>4, r=row&15, ks = 16-byte k-slice (0..255).
__global__ void quant_act(const float* __restrict__ X,
                          signed char* __restrict__ At,
                          float* __restrict__ sx) {
  const int row = blockIdx.x;
  const int t = threadIdx.x;  // 256
  const float* xr = X + (size_t)row * K_DIM;
  float4 v[4];
  float am = 0.f;
#pragma unroll
  for (int c = 0; c < 4; ++c) {
    v[c] = ((const float4*)xr)[c * 256 + t];  // coalesced 16B/lane
    am = fmaxf(am, fmaxf(fmaxf(fabsf(v[c].x), fabsf(v[c].y)),
                         fmaxf(fabsf(v[c].z), fabsf(v[c].w))));
  }
#pragma unroll
  for (int off = 32; off > 0; off >>= 1)
    am = fmaxf(am, __shfl_down(am, off));
  __shared__ float red[4];
  __shared__ float s_inv;
  __shared__ unsigned int shuf[1024];  // 4KB dword shuffle for 16B-chunk writes
  if ((t & 63) == 0) red[t >> 6] = am;
  __syncthreads();
  if (t == 0) {
    float m = fmaxf(fmaxf(red[0], red[1]), fmaxf(red[2], red[3]));
    float scale = fmaxf(m, 1e-6f) / 127.0f;  // matches ref
    sx[row] = scale;
    s_inv = 1.0f / scale;  // one divide per row
  }
  __syncthreads();
  const float inv = s_inv;
#pragma unroll
  for (int c = 0; c < 4; ++c) {
    int q0 = (int)fminf(fmaxf(rintf(v[c].x * inv), -127.f), 127.f);
    int q1 = (int)fminf(fmaxf(rintf(v[c].y * inv), -127.f), 127.f);
    int q2 = (int)fminf(fmaxf(rintf(v[c].z * inv), -127.f), 127.f);
    int q3 = (int)fminf(fmaxf(rintf(v[c].w * inv), -127.f), 127.f);
    shuf[c * 256 + t] = (q0 & 255) | ((q1 & 255) << 8) | ((q2 & 255) << 16) | (q3 << 24);
  }
  __syncthreads();
  // thread t emits the row's 16B k-slice ks=t
  v4i w = *(const v4i*)&shuf[t * 4];
  signed char* dst = At + (size_t)(row >> 4) * 65536 + t * 256 + (row & 15) * 16;
  *(v4i*)dst = w;
}

// ---------------- weight column-amax: 512 partial blocks + combine ----------------
__global__ void wk_amax_part(const float* __restrict__ Kmat, float* __restrict__ part) {
  const int f = blockIdx.x * 256 + threadIdx.x;
  const float* p = Kmat + (size_t)(blockIdx.y * 128) * N_DIM + f;
  float a0 = 0.f, a1 = 0.f, a2 = 0.f, a3 = 0.f;
#pragma unroll 4
  for (int i = 0; i < 32; ++i) {
    a0 = fmaxf(a0, fabsf(p[0 * N_DIM]));
    a1 = fmaxf(a1, fabsf(p[1 * N_DIM]));
    a2 = fmaxf(a2, fabsf(p[2 * N_DIM]));
    a3 = fmaxf(a3, fabsf(p[3 * N_DIM]));
    p += 4 * N_DIM;
  }
  part[(size_t)blockIdx.y * N_DIM + f] = fmaxf(fmaxf(a0, a1), fmaxf(a2, a3));
}

__global__ void wk_amax_comb(const float* __restrict__ part,
                             float* __restrict__ sk, float* __restrict__ skinv) {
  const int f = blockIdx.x * 256 + threadIdx.x;
  float am = 0.f;
#pragma unroll
  for (int s = 0; s < 32; ++s) am = fmaxf(am, part[(size_t)s * N_DIM + f]);
  float scale = fmaxf(am, 1e-6f) / 127.0f;
  sk[f] = scale;
  skinv[f] = 1.0f / scale;
}

// ---------------- weight quant + transpose into B_t[nt][ks][r][16] ----------------
__global__ void wk_quant(const float* __restrict__ Kmat,
                         const float* __restrict__ skinv,
                         signed char* __restrict__ Bt) {
  const int f0 = (blockIdx.x & 63) * 64;
  const int d0 = (blockIdx.x >> 6) * 64;
  const int t = threadIdx.x;
  const int fl = t & 63;
  const int dl0 = t >> 6;  // 0..3
  __shared__ __align__(16) signed char tile[64 * 80];  // stride 80: 16-aligned rows
  const float inv = skinv[f0 + fl];
#pragma unroll
  for (int c = 0; c < 16; ++c) {
    const int dl = c * 4 + dl0;
    float vv = Kmat[(size_t)(d0 + dl) * N_DIM + f0 + fl];  // 256B/row coalesced
    float q = fminf(fmaxf(rintf(vv * inv), -127.f), 127.f);
    tile[fl * 80 + dl] = (signed char)(int)q;
  }
  __syncthreads();
  // one 16B chunk per thread: frow = t>>2 (0..63), ksl = t&3
  const int frow = t >> 2;
  const int ksl = t & 3;
  v4i w = *(const v4i*)&tile[frow * 80 + ksl * 16];
  const int f = f0 + frow;
  signed char* dst = Bt + (size_t)(f >> 4) * 65536 + ((d0 >> 4) + ksl) * 256 + (f & 15) * 16;
  *(v4i*)dst = w;
}

// ---------------- int8 GEMM: 128x128 tile, BK=128, 4 waves, 16x16x64 i8 MFMA ----------------
__global__ __launch_bounds__(256, 2) void gemm_i8(
    const signed char* __restrict__ At, const signed char* __restrict__ Bt,
    const float* __restrict__ sx, const float* __restrict__ sk,
    float* __restrict__ C) {
  const int n0 = blockIdx.x * 128;
  const int m0 = blockIdx.y * 128;
  const int t = threadIdx.x;
  const int lane = t & 63;
  const int wave = t >> 6;
  const int wm = (wave >> 1) * 64;  // wave's 64x64 sub-tile
  const int wn = (wave & 1) * 64;
  const int lrow = lane & 15;
  const int lq = lane >> 4;

  // lds layout mirrors the global fragment-tiled order:
  // lA chunk c (c=0..1023): mt_i=c>>7, ks_l=(c&127)>>4, r=c&15
  __shared__ __align__(16) signed char lds[32768];
  signed char* lA = lds;
  signed char* lB = lds + 16384;

  v4i acc[4][4];
#pragma unroll
  for (int i = 0; i < 4; ++i)
#pragma unroll
    for (int j = 0; j < 4; ++j) acc[i][j] = (v4i){0, 0, 0, 0};

  const signed char* Abase = At + (size_t)(m0 >> 4) * 65536;
  const signed char* Bbase = Bt + (size_t)(n0 >> 4) * 65536;

  // fragment read bases: addr = mt_i*2048 + s*1024 + lane*16  (contiguous per read)
  const int la = ((wave >> 1) * 4) * 2048 + lane * 16;
  const int lb = ((wave & 1) * 4) * 2048 + lane * 16;

  for (int kb = 0; kb < K_DIM; kb += 128) {
    const int kofs = kb * 16;  // (kb/16)*256 bytes into each tile-row
    // stage 16KB A + 16KB B: every wave-instr reads 1KB contiguous global
#pragma unroll
    for (int j = 0; j < 4; ++j) {
      const int c = j * 256 + t;
      const int mt_i = c >> 7;
      const int inner = c & 127;
      __builtin_amdgcn_global_load_lds(
          (g_void_t*)(Abase + (size_t)mt_i * 65536 + kofs + inner * 16),
          (lds_void_t*)(lA + c * 16), 16, 0, 0);
      __builtin_amdgcn_global_load_lds(
          (g_void_t*)(Bbase + (size_t)mt_i * 65536 + kofs + inner * 16),
          (lds_void_t*)(lB + c * 16), 16, 0, 0);
    }
    __syncthreads();
#pragma unroll
    for (int s = 0; s < 2; ++s) {  // two K=64 steps per staging round
      v4i af[4], bf[4];
#pragma unroll
      for (int i = 0; i < 4; ++i) af[i] = *(const v4i*)(lA + la + i * 2048 + s * 1024);
#pragma unroll
      for (int i = 0; i < 4; ++i) bf[i] = *(const v4i*)(lB + lb + i * 2048 + s * 1024);
#pragma unroll
      for (int mi = 0; mi < 4; ++mi)
#pragma unroll
        for (int ni = 0; ni < 4; ++ni)
          acc[mi][ni] =
              __builtin_amdgcn_mfma_i32_16x16x64_i8(af[mi], bf[ni], acc[mi][ni], 0, 0, 0);
    }
    __syncthreads();
  }

  // epilogue: C/D layout col=lane&15, row=(lane>>4)*4+reg (dtype-independent)
#pragma unroll
  for (int mi = 0; mi < 4; ++mi) {
#pragma unroll
    for (int ni = 0; ni < 4; ++ni) {
      const int gn = n0 + wn + ni * 16 + lrow;
      const float skv = sk[gn];
#pragma unroll
      for (int r = 0; r < 4; ++r) {
        const int gm = m0 + wm + mi * 16 + lq * 4 + r;
        C[(size_t)gm * N_DIM + gn] = (float)acc[mi][ni][r] * sx[gm] * skv;
      }
    }
  }
}

// ---------------- launch ----------------
extern "C" void kernel_launch(void* const* d_in, const int* in_sizes, int n_in,
                              void* d_out, int out_size, void* d_ws, size_t ws_size,
                              hipStream_t stream) {
  const float* X = (const float*)d_in[0];  // [4,2048,4096] fp32
  const float* W = (const float*)d_in[1];  // [4096,4096] fp32
  float* out = (float*)d_out;              // [4,2048,4096] fp32
  char* ws = (char*)d_ws;

  signed char* At = (signed char*)ws;                       // 32 MB  tiled A
  signed char* Bt = (signed char*)(ws + 33554432);          // 16 MB  tiled B
  float* sx = (float*)(ws + 50331648);                      // 32 KB
  float* sk = (float*)(ws + 50364416);                      // 16 KB
  float* skinv = (float*)(ws + 50380800);                   // 16 KB
  float* part = (float*)(ws + 50397184);                    // 512 KB

  quant_act<<<M_DIM, 256, 0, stream>>>(X, At, sx);
  wk_amax_part<<<dim3(16, 32), 256, 0, stream>>>(W, part);
  wk_amax_comb<<<16, 256, 0, stream>>>(part, sk, skinv);
  wk_quant<<<4096, 256, 0, stream>>>(W, skinv, Bt);
  gemm_i8<<<dim3(N_DIM / 128, M_DIM / 128), 256, 0, stream>>>(At, Bt, sx, sk, out);
}